// Round 13
// baseline (721.652 us; speedup 1.0000x reference)
//
#include <hip/hip_runtime.h>
#include <hip/hip_bf16.h>

typedef __hip_bfloat16 bf16;
using short8 = __attribute__((ext_vector_type(8))) short;
using f32x4  = __attribute__((ext_vector_type(4))) float;

#define MFMA16(a,b,c) __builtin_amdgcn_mfma_f32_16x16x32_bf16((a),(b),(c),0,0,0)
#define MAXBUCK 4096   // 32-node bins for the sort pipeline: supports N <= 131072
#define SB 72          // LDS stride (bf16 shorts) for S rows (144B, 16B-aligned)
#define MSTR 72        // LDS stride (bf16) for m rows
#define SRCCAP 1024    // staged src indices per bucket (mean 512, 22 sigma headroom)

__device__ __forceinline__ float b2f(bf16 v){ return __bfloat162float(v); }
__device__ __forceinline__ bf16  f2b(float v){ return __float2bfloat16(v); }
__device__ __forceinline__ float sigmf(float x){ return 1.f/(1.f+__expf(-x)); }
__device__ __forceinline__ float tanhfast(float x){
  x = fminf(fmaxf(x,-15.f),15.f);
  float e = __expf(2.f*x);
  return (e-1.f)/(e+1.f);
}
__device__ __forceinline__ short8 ld_frag(const bf16* p){
  return *reinterpret_cast<const short8*>(p);
}
__device__ __forceinline__ float lo16f(unsigned w){
  return __builtin_bit_cast(float, w<<16);
}
__device__ __forceinline__ float hi16f(unsigned w){
  return __builtin_bit_cast(float, w & 0xFFFF0000u);
}
__device__ __forceinline__ short f2bits(float f){
  unsigned u = __builtin_bit_cast(unsigned, f);
  unsigned r = (u + 0x7FFFu + ((u>>16)&1u)) >> 16;
  return (short)r;
}

// ---------------- dtype sniff + canonicalize ----------------

__global__ void k_sniff(const unsigned int* __restrict__ x, int* __restrict__ flag){
  int t = threadIdx.x;
  int good = 0;
  for (int i=t; i<4096; i+=256){
    unsigned w = x[i];
    unsigned e = (w>>23)&0xFFu;
    unsigned m = w & 0x7FFFFFFFu;
    if ((e>=100u && e<=150u) || m==0u) good++;
  }
  __shared__ int sm[256];
  sm[t]=good; __syncthreads();
  if (t==0){ int s=0; for (int k=0;k<256;k++) s+=sm[k]; *flag = (s>2048)?1:0; }
}

struct PtrPack { const void* p[17]; };

#define CAN_X     0
#define CAN_L0W   1500032
#define CAN_L0B   1500992
#define CAN_EE    1501056
#define CAN_CB    1521536
#define CAN_WIH   1521600
#define CAN_WHH   1533888
#define CAN_BIH   1546176
#define CAN_BHH   1546368
#define CAN_IW1   1546560
#define CAN_IB1   1554752
#define CAN_IW2   1554816
#define CAN_IB2   1555584
#define CAN_JW1   1555648
#define CAN_JB1   1559744
#define CAN_JW2   1559808
#define CAN_JB2   1560576
#define CAN_TOT   1560640

__global__ void k_canon(PtrPack pk, const int* __restrict__ flag, bf16* __restrict__ dst){
  static const int offs[17] = {CAN_X,CAN_L0W,CAN_L0B,CAN_EE,CAN_CB,CAN_WIH,CAN_WHH,
    CAN_BIH,CAN_BHH,CAN_IW1,CAN_IB1,CAN_IW2,CAN_IB2,CAN_JW1,CAN_JB1,CAN_JW2,CAN_JB2};
  static const int szs[17]  = {1500000,960,64,20480,64,12288,12288,192,192,8192,64,768,12,4096,64,768,12};
  int t = blockIdx.x*256+threadIdx.x;
  if (t >= CAN_TOT) return;
  int s = 0;
  #pragma unroll
  for (int k=1;k<17;k++) if (t >= offs[k]) s = k;
  int i = t - offs[s];
  float v = 0.f;
  if (i < szs[s]){
    if (*flag) v = ((const float*)pk.p[s])[i];
    else       v = b2f(((const bf16*)pk.p[s])[i]);
  }
  dst[t] = f2b(v);
}

// ---------------- setup kernels ----------------

// batch is sorted: gptr[g] = lower_bound(batch, g)
__global__ void k_gptr(const int* __restrict__ batch, int N_, int G_, int* __restrict__ gptr){
  int g = blockIdx.x*256+threadIdx.x;
  if (g > G_) return;
  int lo=0, hi=N_;
  while (lo<hi){ int mid=(lo+hi)>>1; if (batch[mid] < g) lo=mid+1; else hi=mid; }
  gptr[g]=lo;
}

// single-block exclusive scan (wave shuffle-scan + cross-wave)
__global__ __launch_bounds__(1024) void k_scan(const int* __restrict__ cnt, int n,
      int* __restrict__ ptr, int* __restrict__ cursor){
  __shared__ int ws[17];
  int tid = threadIdx.x, lane = tid&63, w = tid>>6;
  int run = 0;
  for (int base=0; base<n; base+=1024){
    int i = base + tid;
    int v = (i<n)? cnt[i] : 0;
    int incl = v;
    #pragma unroll
    for (int off=1; off<64; off<<=1){
      int t = __shfl_up(incl, off, 64);
      if (lane>=off) incl += t;
    }
    if (lane==63) ws[w] = incl;
    __syncthreads();
    if (tid==0){ int r=0; for (int k=0;k<16;k++){ int t=ws[k]; ws[k]=r; r+=t; } ws[16]=r; }
    __syncthreads();
    int excl = run + ws[w] + incl - v;
    if (i<n){
      ptr[i] = excl;
      if (cursor) cursor[i] = excl;
    }
    run += ws[16];
    __syncthreads();
  }
  if (tid==0) ptr[n] = run;
}

// pass A: per-block LDS histogram of dst>>5
__global__ __launch_bounds__(256) void k_bcount(const int* __restrict__ dstv, int E_,
      int nb, int* __restrict__ bkt_cnt){
  __shared__ int lh[MAXBUCK];
  for (int i=threadIdx.x;i<nb;i+=256) lh[i]=0;
  __syncthreads();
  int base = blockIdx.x*4096;
  int end = min(base+4096, E_);
  for (int i=base+threadIdx.x; i<end; i+=256)
    atomicAdd(&lh[dstv[i]>>5], 1);
  __syncthreads();
  for (int i=threadIdx.x;i<nb;i+=256)
    if (lh[i]) atomicAdd(&bkt_cnt[i], lh[i]);
}

// pass B: rank within (block,bucket), reserve global runs, write packed payload
// payload = key<<17 | src, key = (dst&31)*5+type in [0,160)
__global__ __launch_bounds__(256) void k_bscatter(const int* __restrict__ srcv,
      const int* __restrict__ dstv, const int* __restrict__ eav, int E_, int nb,
      int* __restrict__ cursor, unsigned int* __restrict__ bucketed){
  __shared__ int lh[MAXBUCK];
  __shared__ int lbase[MAXBUCK];
  for (int i=threadIdx.x;i<nb;i+=256) lh[i]=0;
  __syncthreads();
  int base = blockIdx.x*4096;
  int key[16]; int rnk[16]; unsigned pay[16];
  #pragma unroll
  for (int u=0;u<16;u++){
    int i = base + u*256 + threadIdx.x;
    bool valid = i < E_;
    int d = valid? dstv[i] : 0;
    int k = d>>5;
    key[u] = k;
    pay[u] = valid? (((unsigned)((d&31)*5 + eav[i]))<<17) | (unsigned)srcv[i] : 0u;
    rnk[u] = valid? atomicAdd(&lh[k],1) : 0;
  }
  __syncthreads();
  for (int i=threadIdx.x;i<nb;i+=256){
    int c = lh[i];
    lbase[i] = c? atomicAdd(&cursor[i], c) : 0;
  }
  __syncthreads();
  #pragma unroll
  for (int u=0;u<16;u++){
    int i = base + u*256 + threadIdx.x;
    if (i < E_) bucketed[lbase[key[u]] + rnk[u]] = pay[u];
  }
}

// pass C: counting sort within each 32-node bin by key (160 keys);
// kptr indexed by GLOBAL key = dst*5+type. sorted_src is key-sorted src list.
// Also emits, per 16-node step bucket (80 keys), a permutation of local keys
// ranked by segment length (descending) -> length-balanced co-scheduling.
__global__ __launch_bounds__(256) void k_bsort(const unsigned int* __restrict__ bucketed,
      const int* __restrict__ bkt_ptr, int nb, int E_,
      int* __restrict__ kptr, int* __restrict__ sorted_src,
      unsigned char* __restrict__ kperm){
  __shared__ int cnt[160], sc[160], cur[160];
  int tid = threadIdx.x;
  int b = blockIdx.x;
  int s = bkt_ptr[b], e = bkt_ptr[b+1];
  if (tid<160) cnt[tid]=0;
  __syncthreads();
  for (int i=s+tid; i<e; i+=256) atomicAdd(&cnt[bucketed[i]>>17], 1);
  __syncthreads();
  if (tid<160) sc[tid]=cnt[tid];
  __syncthreads();
  #pragma unroll
  for (int off=1; off<160; off<<=1){
    int v = 0;
    if (tid<160 && tid>=off) v = sc[tid-off];
    __syncthreads();
    if (tid<160) sc[tid] += v;
    __syncthreads();
  }
  if (tid<160){
    int base = s + sc[tid] - cnt[tid];
    kptr[b*160+tid] = base;
    cur[tid] = base;
  }
  if (b==nb-1 && tid==0) kptr[(size_t)nb*160] = e;
  // rank keys by length (descending) within each 80-key half
  if (tid<160){
    int hbase = (tid<80)? 0 : 80;
    int me = cnt[tid];
    int r = 0;
    for (int j=0;j<80;j++){
      int jj = hbase+j;
      int cj = cnt[jj];
      r += (cj>me) || (cj==me && jj<tid);
    }
    kperm[((size_t)b*2 + (tid<80?0:1))*80 + r] = (unsigned char)(tid - hbase);
  }
  __syncthreads();
  for (int i=s+tid; i<e; i+=256){
    unsigned p = bucketed[i];
    int pos = atomicAdd(&cur[p>>17], 1);
    sorted_src[pos] = (int)(p & 0x1FFFFu);
  }
}

__global__ __launch_bounds__(256) void k_lin0(const bf16* __restrict__ x,
      const bf16* __restrict__ w, const bf16* __restrict__ b,
      bf16* __restrict__ out0, bf16* __restrict__ h, int N_){
  int idx = blockIdx.x*256+threadIdx.x;
  int n = idx>>6, o = idx&63;
  if (n>=N_) return;
  float acc = b2f(b[o]);
  #pragma unroll
  for (int k=0;k<15;k++) acc += b2f(x[n*15+k]) * b2f(w[k*64+o]);
  bf16 v = f2b(fmaxf(acc,0.f));
  out0[idx]=v; h[idx]=v;
}

// swizzle edge_embed [5][64][64] -> B-frags for K=320 GEMM.
__global__ void k_swz_wall2(const bf16* __restrict__ ee, unsigned short* __restrict__ dst){
  int t = blockIdx.x*256+threadIdx.x;
  if (t>=2560) return;          // 40 frags * 64 lanes
  int lane=t&63, frag=t>>6, ct=frag/10, ks=frag%10;
  int c = ct*16 + (lane&15);
  #pragma unroll
  for (int j=0;j<8;j++){
    int k = ks*32 + ((lane>>4)<<3) + j;   // global K in [0,320)
    int tt = k>>6, kc = k&63;
    dst[t*8+j] = ((const unsigned short*)ee)[tt*4096 + kc*64 + c];
  }
}

// generic row-major [K][NC] -> B-frag layout (zero-padded cols)
__global__ void k_swz_gen(const unsigned short* __restrict__ src, int KS, int NC,
                          unsigned short* __restrict__ dst, int nfrag){
  int t = blockIdx.x*256+threadIdx.x;
  if (t >= nfrag*64) return;
  int lane=t&63, frag=t>>6, cb=frag/KS, ks=frag%KS;
  int c = cb*16 + (lane&15);
  #pragma unroll
  for (int j=0;j<8;j++){
    int k = ks*32 + ((lane>>4)<<3) + j;
    dst[t*8+j] = (c<NC)? src[k*NC+c] : (unsigned short)0;
  }
}

// ---------------- fused step: gather + NNConv + GRU ----------------
// One block (256 thr = 4 waves) per bucket of 16 dst nodes (80 keys).
// __launch_bounds__(256,8): 8 blocks/CU (32 waves/CU) — LDS 16.4KB x 8 = 131KB,
// VGPR<=64 target (was 32 at 6 waves) for max latency hiding on the gather.
__global__ __launch_bounds__(256,8) void k_step(const bf16* __restrict__ hin,
      bf16* __restrict__ hout,
      const int* __restrict__ sorted_src, const int* __restrict__ kptr,
      const unsigned char* __restrict__ kperm,
      const unsigned short* __restrict__ wall, const unsigned short* __restrict__ wgru,
      const bf16* __restrict__ conv_bias, const bf16* __restrict__ bih,
      const bf16* __restrict__ bhh, int N_){
  __shared__ unsigned short Sb[80*SB];
  __shared__ int kp[81];
  __shared__ unsigned char pm[80];
  __shared__ char ubuf[SRCCAP*4];            // srcL (phase 0/1) | m_s (phase 2/3)
  int* srcL = (int*)ubuf;
  unsigned short* m_s = (unsigned short*)ubuf;
  int tid=threadIdx.x, lane=tid&63, w=tid>>6;
  int b=blockIdx.x;
  if (tid<81) kp[tid]=kptr[(size_t)b*80+tid];
  if (tid<80) pm[tid]=kperm[(size_t)b*80+tid];
  __syncthreads();
  int s0g = kp[0];
  int elen = kp[80]-s0g;
  int cap = (elen<=SRCCAP)? elen : 0;        // fallback: read global if oversized
  for (int i=tid;i<cap;i+=256) srcL[i]=sorted_src[s0g+i];
  __syncthreads();
  int g=lane>>3, c=lane&7;
  const bf16* hp = hin + c*8;

  // ---- phase 1 ----
  auto run_phase1 = [&](auto GET){
    #pragma unroll 1
    for (int jo=0;jo<5;jo++){
      int pbase = jo*16 + w*4;
      int p  = pm[pbase + (g&3)];
      int p0 = pm[pbase];
      int st = kp[p]-s0g, len = kp[p+1]-kp[p];
      int maxLen = kp[p0+1]-kp[p0];          // rank-0 key is longest of the 4
      int sub = g>>2;
      float a[8];
      #pragma unroll
      for (int j=0;j<8;j++) a[j]=0.f;
      for (int base=0; base<maxLen; base+=8){
        uint4 hv[4];
        #pragma unroll
        for (int u=0;u<4;u++){
          int idx = base + sub*4 + u;
          hv[u].x=0u; hv[u].y=0u; hv[u].z=0u; hv[u].w=0u;
          if (idx < len){
            int s = GET(st+idx);
            hv[u] = *(const uint4*)(hp + (size_t)s*64);
          }
        }
        #pragma unroll
        for (int u=0;u<4;u++){
          a[0]+=lo16f(hv[u].x); a[1]+=hi16f(hv[u].x);
          a[2]+=lo16f(hv[u].y); a[3]+=hi16f(hv[u].y);
          a[4]+=lo16f(hv[u].z); a[5]+=hi16f(hv[u].z);
          a[6]+=lo16f(hv[u].w); a[7]+=hi16f(hv[u].w);
        }
      }
      #pragma unroll
      for (int j=0;j<8;j++) a[j] += __shfl_xor(a[j], 32);
      if (g<4){
        short8 v;
        #pragma unroll
        for (int j=0;j<8;j++) v[j] = f2bits(a[j]);
        *reinterpret_cast<short8*>(&Sb[(size_t)p*SB + c*8]) = v;
      }
    }
  };
  if (cap) run_phase1([&](int rel){ return srcL[rel]; });
  else     run_phase1([&](int rel){ return sorted_src[s0g+rel]; });
  __syncthreads();

  // ---- phase 2: wave w -> coltile ct=w ----
  int q=lane>>4, mr=lane&15;
  {
    int ct = w;
    f32x4 acc={0.f,0.f,0.f,0.f};
    #pragma unroll
    for (int ks=0;ks<10;ks++){
      int k0 = ks*32 + q*8;
      int tt = k0>>6, ch = k0&63;
      short8 af = *reinterpret_cast<const short8*>(&Sb[(size_t)(mr*5+tt)*SB + ch]);
      short8 bfrag = *(const short8*)(wall + (size_t)((ct*10+ks)*64+lane)*8);
      acc = MFMA16(af, bfrag, acc);
    }
    int col = ct*16+mr;
    float bi = b2f(conv_bias[col]);
    #pragma unroll
    for (int r=0;r<4;r++){
      int nl = q*4+r;
      int deg = kp[nl*5+5]-kp[nl*5];
      float dv = 1.f/fmaxf((float)deg,1.f);
      m_s[nl*MSTR+col] = (unsigned short)f2bits(fmaxf(acc[r]*dv+bi,0.f));
    }
  }
  __syncthreads();

  // ---- phase 3: GRU, wave w -> coltile cc=w ----
  {
    int cc = w;
    int na = b*16+mr; if (na>N_-1) na=N_-1;
    short8 am0 = *(const short8*)(&m_s[mr*MSTR + q*8]);
    short8 am1 = *(const short8*)(&m_s[mr*MSTR + 32 + q*8]);
    short8 ah0 = ld_frag(hin + (size_t)na*64 + q*8);
    short8 ah1 = ld_frag(hin + (size_t)na*64 + 32 + q*8);
    const short8* Bw = reinterpret_cast<const short8*>(wgru);
    f32x4 xr={0.f,0.f,0.f,0.f}, xz=xr, xn=xr, hr=xr, hz=xr, hn=xr;
    xr = MFMA16(am0, Bw[((cc  )*2+0)*64+lane], xr);
    xr = MFMA16(am1, Bw[((cc  )*2+1)*64+lane], xr);
    xz = MFMA16(am0, Bw[((cc+4)*2+0)*64+lane], xz);
    xz = MFMA16(am1, Bw[((cc+4)*2+1)*64+lane], xz);
    xn = MFMA16(am0, Bw[((cc+8)*2+0)*64+lane], xn);
    xn = MFMA16(am1, Bw[((cc+8)*2+1)*64+lane], xn);
    hr = MFMA16(ah0, Bw[(24+(cc  )*2+0)*64+lane], hr);
    hr = MFMA16(ah1, Bw[(24+(cc  )*2+1)*64+lane], hr);
    hz = MFMA16(ah0, Bw[(24+(cc+4)*2+0)*64+lane], hz);
    hz = MFMA16(ah1, Bw[(24+(cc+4)*2+1)*64+lane], hz);
    hn = MFMA16(ah0, Bw[(24+(cc+8)*2+0)*64+lane], hn);
    hn = MFMA16(ah1, Bw[(24+(cc+8)*2+1)*64+lane], hn);
    int col = cc*16+mr;
    float bxr=b2f(bih[col]), bxz=b2f(bih[col+64]), bxn=b2f(bih[col+128]);
    float bhr=b2f(bhh[col]), bhz=b2f(bhh[col+64]), bhn=b2f(bhh[col+128]);
    #pragma unroll
    for (int r=0;r<4;r++){
      int row = q*4+r;
      int n = b*16+row;
      if (n < N_){
        float rg = sigmf(xr[r]+bxr + hr[r]+bhr);
        float zg = sigmf(xz[r]+bxz + hz[r]+bhz);
        float ng = tanhfast(xn[r]+bxn + rg*(hn[r]+bhn));
        float ho = b2f(hin[(size_t)n*64+col]);
        hout[(size_t)n*64+col] = f2b((1.f-zg)*ng + zg*ho);
      }
    }
  }
}

// ---------------- readout ----------------

__global__ __launch_bounds__(256) void k_read1(const bf16* __restrict__ h, const bf16* __restrict__ out0,
      const unsigned short* __restrict__ W, const bf16* __restrict__ ib1, const bf16* __restrict__ jb1,
      bf16* __restrict__ s1, bf16* __restrict__ t1, int N_){
  __shared__ unsigned short lds[12288];
  { const int* s=(const int*)W; int* d=(int*)lds;
    for (int i=threadIdx.x;i<6144;i+=256) d[i]=s[i]; }
  __syncthreads();
  int tid=threadIdx.x, lane=tid&63, w=tid>>6, q=lane>>4;
  int nb = blockIdx.x*64 + w*16;
  int ar = nb + (lane&15); if (ar>N_-1) ar=N_-1;
  short8 ah0 = ld_frag(h + (size_t)ar*64 + q*8),    ah1 = ld_frag(h + (size_t)ar*64 + 32 + q*8);
  short8 ao0 = ld_frag(out0 + (size_t)ar*64 + q*8), ao1 = ld_frag(out0 + (size_t)ar*64 + 32 + q*8);
  const short8* Bi = reinterpret_cast<const short8*>(lds);
  const short8* Bj = reinterpret_cast<const short8*>(lds + 8192);
  int colb = lane&15;
  for (int cb=0; cb<4; cb++){
    f32x4 ai = {0.f,0.f,0.f,0.f};
    ai = MFMA16(ah0, Bi[(cb*4+0)*64+lane], ai);
    ai = MFMA16(ah1, Bi[(cb*4+1)*64+lane], ai);
    ai = MFMA16(ao0, Bi[(cb*4+2)*64+lane], ai);
    ai = MFMA16(ao1, Bi[(cb*4+3)*64+lane], ai);
    f32x4 aj = {0.f,0.f,0.f,0.f};
    aj = MFMA16(ah0, Bj[(cb*2+0)*64+lane], aj);
    aj = MFMA16(ah1, Bj[(cb*2+1)*64+lane], aj);
    int col = cb*16 + colb;
    float bi=b2f(ib1[col]), bj=b2f(jb1[col]);
    #pragma unroll
    for (int r=0;r<4;r++){
      int row = nb + q*4 + r;
      if (row < N_){
        s1[(size_t)row*64+col] = f2b(sigmf(ai[r]+bi));
        t1[(size_t)row*64+col] = f2b(sigmf(aj[r]+bj));
      }
    }
  }
}

__global__ __launch_bounds__(256) void k_read2(const bf16* __restrict__ s1, const bf16* __restrict__ t1,
      const unsigned short* __restrict__ iw2swz, const unsigned short* __restrict__ jw2swz,
      const bf16* __restrict__ ib2, const bf16* __restrict__ jb2,
      float* __restrict__ gated, int N_){
  int tid=threadIdx.x, lane=tid&63, w=tid>>6, q=lane>>4;
  int nb = blockIdx.x*64 + w*16;
  int ar = nb + (lane&15); if (ar>N_-1) ar=N_-1;
  short8 as0 = ld_frag(s1 + (size_t)ar*64 + q*8), as1 = ld_frag(s1 + (size_t)ar*64 + 32 + q*8);
  short8 at0 = ld_frag(t1 + (size_t)ar*64 + q*8), at1 = ld_frag(t1 + (size_t)ar*64 + 32 + q*8);
  const short8* Bi = reinterpret_cast<const short8*>(iw2swz);
  const short8* Bj = reinterpret_cast<const short8*>(jw2swz);
  f32x4 ai = {0.f,0.f,0.f,0.f};
  ai = MFMA16(as0, Bi[lane], ai);
  ai = MFMA16(as1, Bi[64+lane], ai);
  f32x4 aj = {0.f,0.f,0.f,0.f};
  aj = MFMA16(at0, Bj[lane], aj);
  aj = MFMA16(at1, Bj[64+lane], aj);
  int col = lane&15;
  if (col<12){
    float bi=b2f(ib2[col]), bj=b2f(jb2[col]);
    #pragma unroll
    for (int r=0;r<4;r++){
      int row = nb + q*4 + r;
      if (row < N_) gated[(size_t)row*12+col] = sigmf(ai[r]+bi)*(aj[r]+bj);
    }
  }
}

__global__ __launch_bounds__(256) void k_graphsum(const float* __restrict__ gated,
      const int* __restrict__ gptr, const int* __restrict__ flag, void* __restrict__ outp){
  int g = blockIdx.x;
  int s = gptr[g], e = gptr[g+1];
  int tid = threadIdx.x;
  int c = tid & 15, rg = tid >> 4;
  float acc = 0.f;
  if (c < 12)
    for (int row = s + rg; row < e; row += 16) acc += gated[(size_t)row*12 + c];
  __shared__ float sm[256];
  sm[tid] = acc;
  __syncthreads();
  if (rg == 0 && c < 12){
    float t = 0.f;
    for (int k=0;k<16;k++) t += sm[k*16 + c];
    if (*flag) ((float*)outp)[g*12 + c] = t;
    else       ((bf16*) outp)[g*12 + c] = f2b(t);
  }
}

// ---------------- launch ----------------

extern "C" void kernel_launch(void* const* d_in, const int* in_sizes, int n_in,
                              void* d_out, int out_size, void* d_ws, size_t ws_size,
                              hipStream_t stream){
  const int*  ei    = (const int*) d_in[1];
  const int*  ea    = (const int*) d_in[2];
  const int*  batch = (const int*) d_in[3];

  const int N_ = in_sizes[3];        // 100000
  const int E_ = in_sizes[2];        // 3200000
  const int G_ = out_size / 12;      // 256
  const int nb  = (N_ + 31) >> 5;    // 3125 bins of 32 nodes (sort pipeline)
  const int nbs = (N_ + 15) >> 4;    // 6250 buckets of 16 nodes (step kernel)

  char* ws = (char*)d_ws;
  size_t off = 0;
  auto alloc = [&](size_t bytes)->size_t{
    size_t o = off; off += (bytes + 255) & ~(size_t)255; return o;
  };

  size_t oOut0   = alloc((size_t)N_*64*2);
  size_t oH0     = alloc((size_t)N_*64*2);
  size_t oH1     = alloc((size_t)N_*64*2);
  size_t oS1     = alloc((size_t)N_*64*2);
  size_t oT1     = alloc((size_t)N_*64*2);
  size_t oGated  = alloc((size_t)N_*12*4);
  size_t oBEdges = alloc((size_t)E_*4);
  size_t oSorted = alloc((size_t)E_*4);
  size_t oKptr   = alloc(((size_t)nb*160+2)*4);
  size_t oKperm  = alloc((size_t)nb*160);
  size_t oCanon  = alloc((size_t)CAN_TOT*2);
  size_t oCnt    = alloc((size_t)nb*4);
  size_t oBPtr   = alloc((size_t)(nb+1)*4);
  size_t oBCur   = alloc((size_t)nb*4);
  size_t oGptr   = alloc((size_t)(G_+1)*4);
  size_t oFlag   = alloc(256);
  size_t oWall   = alloc((size_t)20480*2);
  size_t oWgru   = alloc((size_t)24576*2);
  size_t oWr1    = alloc((size_t)12288*2);
  size_t oWiw2   = alloc((size_t)1024*2);
  size_t oWjw2   = alloc((size_t)1024*2);

  bf16*  out0    = (bf16*)(ws + oOut0);
  bf16*  h0      = (bf16*)(ws + oH0);
  bf16*  h1      = (bf16*)(ws + oH1);
  bf16*  s1      = (bf16*)(ws + oS1);
  bf16*  t1      = (bf16*)(ws + oT1);
  float* gated   = (float*)(ws + oGated);
  unsigned int* bucketed = (unsigned int*)(ws + oBEdges);
  int*   sorted_src = (int*)(ws + oSorted);
  int*   kptr    = (int*)(ws + oKptr);
  unsigned char* kperm = (unsigned char*)(ws + oKperm);
  bf16*  can     = (bf16*)(ws + oCanon);
  int*   bkt_cnt = (int*)(ws + oCnt);
  int*   bkt_ptr = (int*)(ws + oBPtr);
  int*   bkt_cur = (int*)(ws + oBCur);
  int*   gptr    = (int*)(ws + oGptr);
  int*   flag    = (int*)(ws + oFlag);
  unsigned short* wall  = (unsigned short*)(ws + oWall);
  unsigned short* wgru  = (unsigned short*)(ws + oWgru);
  unsigned short* wr1   = (unsigned short*)(ws + oWr1);
  unsigned short* wiw2s = (unsigned short*)(ws + oWiw2);
  unsigned short* wjw2s = (unsigned short*)(ws + oWjw2);

  const bf16* xC    = can + CAN_X;
  const bf16* l0wC  = can + CAN_L0W;
  const bf16* l0bC  = can + CAN_L0B;
  const bf16* eeC   = can + CAN_EE;
  const bf16* cbC   = can + CAN_CB;
  const bf16* wihC  = can + CAN_WIH;
  const bf16* whhC  = can + CAN_WHH;
  const bf16* bihC  = can + CAN_BIH;
  const bf16* bhhC  = can + CAN_BHH;
  const bf16* iw1C  = can + CAN_IW1;
  const bf16* ib1C  = can + CAN_IB1;
  const bf16* iw2C  = can + CAN_IW2;
  const bf16* ib2C  = can + CAN_IB2;
  const bf16* jw1C  = can + CAN_JW1;
  const bf16* jb1C  = can + CAN_JB1;
  const bf16* jw2C  = can + CAN_JW2;
  const bf16* jb2C  = can + CAN_JB2;

  PtrPack pk;
  pk.p[0]=d_in[0];  pk.p[1]=d_in[4];  pk.p[2]=d_in[5];  pk.p[3]=d_in[6];
  pk.p[4]=d_in[7];  pk.p[5]=d_in[8];  pk.p[6]=d_in[9];  pk.p[7]=d_in[10];
  pk.p[8]=d_in[11]; pk.p[9]=d_in[12]; pk.p[10]=d_in[13]; pk.p[11]=d_in[14];
  pk.p[12]=d_in[15]; pk.p[13]=d_in[16]; pk.p[14]=d_in[17]; pk.p[15]=d_in[18];
  pk.p[16]=d_in[19];

  const int gNw  = (N_+63)/64;       // 64 nodes / block (readout)
  const int gEc  = (E_+4095)/4096;   // 4096-edge chunks

  // --- setup ---
  k_sniff<<<1, 256, 0, stream>>>((const unsigned int*)d_in[0], flag);
  k_canon<<<(CAN_TOT+255)/256, 256, 0, stream>>>(pk, flag, can);
  hipMemsetAsync(ws + oCnt, 0, (size_t)nb*4, stream);
  k_gptr<<<(G_+256)/256, 256, 0, stream>>>(batch, N_, G_, gptr);
  k_bcount<<<gEc, 256, 0, stream>>>(ei + E_, E_, nb, bkt_cnt);
  k_scan<<<1, 1024, 0, stream>>>(bkt_cnt, nb, bkt_ptr, bkt_cur);
  k_bscatter<<<gEc, 256, 0, stream>>>(ei, ei + E_, ea, E_, nb, bkt_cur, bucketed);
  k_bsort<<<nb, 256, 0, stream>>>(bucketed, bkt_ptr, nb, E_, kptr, sorted_src, kperm);
  k_lin0<<<(N_*64+255)/256, 256, 0, stream>>>(xC, l0wC, l0bC, out0, h0, N_);
  k_swz_wall2<<<10, 256, 0, stream>>>(eeC, wall);
  k_swz_gen<<<6, 256, 0, stream>>>((const unsigned short*)wihC, 2, 192, wgru,          24);
  k_swz_gen<<<6, 256, 0, stream>>>((const unsigned short*)whhC, 2, 192, wgru + 12288,  24);
  k_swz_gen<<<4, 256, 0, stream>>>((const unsigned short*)iw1C, 4,  64, wr1,           16);
  k_swz_gen<<<2, 256, 0, stream>>>((const unsigned short*)jw1C, 2,  64, wr1 + 8192,     8);
  k_swz_gen<<<1, 256, 0, stream>>>((const unsigned short*)iw2C, 2,  12, wiw2s,          2);
  k_swz_gen<<<1, 256, 0, stream>>>((const unsigned short*)jw2C, 2,  12, wjw2s,          2);

  // --- 6 propagation steps (double-buffered h) ---
  bf16* hb[2] = {h0, h1};
  for (int step = 0; step < 6; ++step){
    k_step<<<nbs, 256, 0, stream>>>(hb[step&1], hb[(step+1)&1], sorted_src, kptr, kperm,
                                    wall, wgru, cbC, bihC, bhhC, N_);
  }
  bf16* hfin = hb[0];   // after 6 steps

  // --- readout ---
  k_read1<<<gNw, 256, 0, stream>>>(hfin, out0, wr1, ib1C, jb1C, s1, t1, N_);
  k_read2<<<gNw, 256, 0, stream>>>(s1, t1, wiw2s, wjw2s, ib2C, jb2C, gated, N_);
  k_graphsum<<<G_, 256, 0, stream>>>(gated, gptr, flag, d_out);
}

// Round 14
// 707.060 us; speedup vs baseline: 1.0206x; 1.0206x over previous
//
#include <hip/hip_runtime.h>
#include <hip/hip_bf16.h>

typedef __hip_bfloat16 bf16;
using short8 = __attribute__((ext_vector_type(8))) short;
using f32x4  = __attribute__((ext_vector_type(4))) float;

#define MFMA16(a,b,c) __builtin_amdgcn_mfma_f32_16x16x32_bf16((a),(b),(c),0,0,0)
#define MAXBUCK 4096   // 32-node bins for the sort pipeline: supports N <= 131072
#define SB 72          // LDS stride (bf16 shorts) for S rows (144B, 16B-aligned)
#define MSTR 72        // LDS stride (bf16) for m rows
#define SRCCAP 1024    // staged src indices per bucket (mean 512, 22 sigma headroom)

__device__ __forceinline__ float b2f(bf16 v){ return __bfloat162float(v); }
__device__ __forceinline__ bf16  f2b(float v){ return __float2bfloat16(v); }
__device__ __forceinline__ float sigmf(float x){ return 1.f/(1.f+__expf(-x)); }
__device__ __forceinline__ float tanhfast(float x){
  x = fminf(fmaxf(x,-15.f),15.f);
  float e = __expf(2.f*x);
  return (e-1.f)/(e+1.f);
}
__device__ __forceinline__ short8 ld_frag(const bf16* p){
  return *reinterpret_cast<const short8*>(p);
}
__device__ __forceinline__ float lo16f(unsigned w){
  return __builtin_bit_cast(float, w<<16);
}
__device__ __forceinline__ float hi16f(unsigned w){
  return __builtin_bit_cast(float, w & 0xFFFF0000u);
}
__device__ __forceinline__ short f2bits(float f){
  unsigned u = __builtin_bit_cast(unsigned, f);
  unsigned r = (u + 0x7FFFu + ((u>>16)&1u)) >> 16;
  return (short)r;
}

// ---------------- dtype sniff + canonicalize ----------------

__global__ void k_sniff(const unsigned int* __restrict__ x, int* __restrict__ flag){
  int t = threadIdx.x;
  int good = 0;
  for (int i=t; i<4096; i+=256){
    unsigned w = x[i];
    unsigned e = (w>>23)&0xFFu;
    unsigned m = w & 0x7FFFFFFFu;
    if ((e>=100u && e<=150u) || m==0u) good++;
  }
  __shared__ int sm[256];
  sm[t]=good; __syncthreads();
  if (t==0){ int s=0; for (int k=0;k<256;k++) s+=sm[k]; *flag = (s>2048)?1:0; }
}

struct PtrPack { const void* p[17]; };

#define CAN_X     0
#define CAN_L0W   1500032
#define CAN_L0B   1500992
#define CAN_EE    1501056
#define CAN_CB    1521536
#define CAN_WIH   1521600
#define CAN_WHH   1533888
#define CAN_BIH   1546176
#define CAN_BHH   1546368
#define CAN_IW1   1546560
#define CAN_IB1   1554752
#define CAN_IW2   1554816
#define CAN_IB2   1555584
#define CAN_JW1   1555648
#define CAN_JB1   1559744
#define CAN_JW2   1559808
#define CAN_JB2   1560576
#define CAN_TOT   1560640

__global__ void k_canon(PtrPack pk, const int* __restrict__ flag, bf16* __restrict__ dst){
  static const int offs[17] = {CAN_X,CAN_L0W,CAN_L0B,CAN_EE,CAN_CB,CAN_WIH,CAN_WHH,
    CAN_BIH,CAN_BHH,CAN_IW1,CAN_IB1,CAN_IW2,CAN_IB2,CAN_JW1,CAN_JB1,CAN_JW2,CAN_JB2};
  static const int szs[17]  = {1500000,960,64,20480,64,12288,12288,192,192,8192,64,768,12,4096,64,768,12};
  int t = blockIdx.x*256+threadIdx.x;
  if (t >= CAN_TOT) return;
  int s = 0;
  #pragma unroll
  for (int k=1;k<17;k++) if (t >= offs[k]) s = k;
  int i = t - offs[s];
  float v = 0.f;
  if (i < szs[s]){
    if (*flag) v = ((const float*)pk.p[s])[i];
    else       v = b2f(((const bf16*)pk.p[s])[i]);
  }
  dst[t] = f2b(v);
}

// ---------------- setup kernels ----------------

// single-block exclusive scan (wave shuffle-scan + cross-wave)
__global__ __launch_bounds__(1024) void k_scan(const int* __restrict__ cnt, int n,
      int* __restrict__ ptr, int* __restrict__ cursor){
  __shared__ int ws[17];
  int tid = threadIdx.x, lane = tid&63, w = tid>>6;
  int run = 0;
  for (int base=0; base<n; base+=1024){
    int i = base + tid;
    int v = (i<n)? cnt[i] : 0;
    int incl = v;
    #pragma unroll
    for (int off=1; off<64; off<<=1){
      int t = __shfl_up(incl, off, 64);
      if (lane>=off) incl += t;
    }
    if (lane==63) ws[w] = incl;
    __syncthreads();
    if (tid==0){ int r=0; for (int k=0;k<16;k++){ int t=ws[k]; ws[k]=r; r+=t; } ws[16]=r; }
    __syncthreads();
    int excl = run + ws[w] + incl - v;
    if (i<n){
      ptr[i] = excl;
      if (cursor) cursor[i] = excl;
    }
    run += ws[16];
    __syncthreads();
  }
  if (tid==0) ptr[n] = run;
}

// pass A: per-block LDS histogram of dst>>5
__global__ __launch_bounds__(256) void k_bcount(const int* __restrict__ dstv, int E_,
      int nb, int* __restrict__ bkt_cnt){
  __shared__ int lh[MAXBUCK];
  for (int i=threadIdx.x;i<nb;i+=256) lh[i]=0;
  __syncthreads();
  int base = blockIdx.x*4096;
  int end = min(base+4096, E_);
  for (int i=base+threadIdx.x; i<end; i+=256)
    atomicAdd(&lh[dstv[i]>>5], 1);
  __syncthreads();
  for (int i=threadIdx.x;i<nb;i+=256)
    if (lh[i]) atomicAdd(&bkt_cnt[i], lh[i]);
}

// pass B: rank within (block,bucket), reserve global runs, write packed payload
// payload = key<<17 | src, key = (dst&31)*5+type in [0,160)
__global__ __launch_bounds__(256) void k_bscatter(const int* __restrict__ srcv,
      const int* __restrict__ dstv, const int* __restrict__ eav, int E_, int nb,
      int* __restrict__ cursor, unsigned int* __restrict__ bucketed){
  __shared__ int lh[MAXBUCK];
  __shared__ int lbase[MAXBUCK];
  for (int i=threadIdx.x;i<nb;i+=256) lh[i]=0;
  __syncthreads();
  int base = blockIdx.x*4096;
  int key[16]; int rnk[16]; unsigned pay[16];
  #pragma unroll
  for (int u=0;u<16;u++){
    int i = base + u*256 + threadIdx.x;
    bool valid = i < E_;
    int d = valid? dstv[i] : 0;
    int k = d>>5;
    key[u] = k;
    pay[u] = valid? (((unsigned)((d&31)*5 + eav[i]))<<17) | (unsigned)srcv[i] : 0u;
    rnk[u] = valid? atomicAdd(&lh[k],1) : 0;
  }
  __syncthreads();
  for (int i=threadIdx.x;i<nb;i+=256){
    int c = lh[i];
    lbase[i] = c? atomicAdd(&cursor[i], c) : 0;
  }
  __syncthreads();
  #pragma unroll
  for (int u=0;u<16;u++){
    int i = base + u*256 + threadIdx.x;
    if (i < E_) bucketed[lbase[key[u]] + rnk[u]] = pay[u];
  }
}

// pass C: counting sort within each 32-node bin by key (160 keys);
// kptr indexed by GLOBAL key = dst*5+type. sorted_src is key-sorted src list.
// Also emits, per 16-node step bucket (80 keys), a permutation of local keys
// ranked by segment length (descending) -> length-balanced co-scheduling.
__global__ __launch_bounds__(256) void k_bsort(const unsigned int* __restrict__ bucketed,
      const int* __restrict__ bkt_ptr, int nb, int E_,
      int* __restrict__ kptr, int* __restrict__ sorted_src,
      unsigned char* __restrict__ kperm){
  __shared__ int cnt[160], sc[160], cur[160];
  int tid = threadIdx.x;
  int b = blockIdx.x;
  int s = bkt_ptr[b], e = bkt_ptr[b+1];
  if (tid<160) cnt[tid]=0;
  __syncthreads();
  for (int i=s+tid; i<e; i+=256) atomicAdd(&cnt[bucketed[i]>>17], 1);
  __syncthreads();
  if (tid<160) sc[tid]=cnt[tid];
  __syncthreads();
  #pragma unroll
  for (int off=1; off<160; off<<=1){
    int v = 0;
    if (tid<160 && tid>=off) v = sc[tid-off];
    __syncthreads();
    if (tid<160) sc[tid] += v;
    __syncthreads();
  }
  if (tid<160){
    int base = s + sc[tid] - cnt[tid];
    kptr[b*160+tid] = base;
    cur[tid] = base;
  }
  if (b==nb-1 && tid==0) kptr[(size_t)nb*160] = e;
  // rank keys by length (descending) within each 80-key half
  if (tid<160){
    int hbase = (tid<80)? 0 : 80;
    int me = cnt[tid];
    int r = 0;
    for (int j=0;j<80;j++){
      int jj = hbase+j;
      int cj = cnt[jj];
      r += (cj>me) || (cj==me && jj<tid);
    }
    kperm[((size_t)b*2 + (tid<80?0:1))*80 + r] = (unsigned char)(tid - hbase);
  }
  __syncthreads();
  for (int i=s+tid; i<e; i+=256){
    unsigned p = bucketed[i];
    int pos = atomicAdd(&cur[p>>17], 1);
    sorted_src[pos] = (int)(p & 0x1FFFFu);
  }
}

__global__ __launch_bounds__(256) void k_lin0(const bf16* __restrict__ x,
      const bf16* __restrict__ w, const bf16* __restrict__ b,
      bf16* __restrict__ out0, bf16* __restrict__ h, int N_){
  int idx = blockIdx.x*256+threadIdx.x;
  int n = idx>>6, o = idx&63;
  if (n>=N_) return;
  float acc = b2f(b[o]);
  #pragma unroll
  for (int k=0;k<15;k++) acc += b2f(x[n*15+k]) * b2f(w[k*64+o]);
  bf16 v = f2b(fmaxf(acc,0.f));
  out0[idx]=v; h[idx]=v;
}

// generic row-major [K][NC] -> B-frag layout (zero-padded cols)
__device__ __forceinline__ void d_swz(const unsigned short* src, int KS, int NC,
                                      unsigned short* dst, int nfrag, int t){
  if (t >= nfrag*64) return;
  int lane=t&63, frag=t>>6, cb=frag/KS, ks=frag%KS;
  int c = cb*16 + (lane&15);
  #pragma unroll
  for (int j=0;j<8;j++){
    int k = ks*32 + ((lane>>4)<<3) + j;
    dst[t*8+j] = (c<NC)? src[k*NC+c] : (unsigned short)0;
  }
}

// fused prep: wall swizzle (blk 0..9), wih (10..15), whh (16..21), iw1 (22..25),
// jw1 (26..27), iw2 (28), jw2 (29), gptr (30..31)
__global__ __launch_bounds__(256) void k_prep(const bf16* __restrict__ ee,
      const bf16* __restrict__ wih, const bf16* __restrict__ whh,
      const bf16* __restrict__ iw1, const bf16* __restrict__ jw1,
      const bf16* __restrict__ iw2, const bf16* __restrict__ jw2,
      unsigned short* __restrict__ wall, unsigned short* __restrict__ wgru,
      unsigned short* __restrict__ wr1, unsigned short* __restrict__ wiw2s,
      unsigned short* __restrict__ wjw2s,
      const int* __restrict__ batch, int N_, int G_, int* __restrict__ gptr){
  int blk = blockIdx.x, tid = threadIdx.x;
  if (blk < 10){
    int t = blk*256+tid;
    if (t<2560){
      int lane=t&63, frag=t>>6, ct=frag/10, ks=frag%10;
      int c = ct*16 + (lane&15);
      #pragma unroll
      for (int j=0;j<8;j++){
        int k = ks*32 + ((lane>>4)<<3) + j;
        int tt = k>>6, kc = k&63;
        wall[t*8+j] = ((const unsigned short*)ee)[tt*4096 + kc*64 + c];
      }
    }
  } else if (blk < 16){
    d_swz((const unsigned short*)wih, 2, 192, wgru, 24, (blk-10)*256+tid);
  } else if (blk < 22){
    d_swz((const unsigned short*)whh, 2, 192, wgru+12288, 24, (blk-16)*256+tid);
  } else if (blk < 26){
    d_swz((const unsigned short*)iw1, 4, 64, wr1, 16, (blk-22)*256+tid);
  } else if (blk < 28){
    d_swz((const unsigned short*)jw1, 2, 64, wr1+8192, 8, (blk-26)*256+tid);
  } else if (blk == 28){
    d_swz((const unsigned short*)iw2, 2, 12, wiw2s, 2, tid);
  } else if (blk == 29){
    d_swz((const unsigned short*)jw2, 2, 12, wjw2s, 2, tid);
  } else {
    int g = (blk-30)*256+tid;
    if (g <= G_){
      int lo=0, hi=N_;
      while (lo<hi){ int mid=(lo+hi)>>1; if (batch[mid] < g) lo=mid+1; else hi=mid; }
      gptr[g]=lo;
    }
  }
}

// ---------------- fused step: gather + NNConv + GRU ----------------
// One block (256 thr = 4 waves) per bucket of 16 dst nodes (80 keys).
__global__ __launch_bounds__(256,8) void k_step(const bf16* __restrict__ hin,
      bf16* __restrict__ hout,
      const int* __restrict__ sorted_src, const int* __restrict__ kptr,
      const unsigned char* __restrict__ kperm,
      const unsigned short* __restrict__ wall, const unsigned short* __restrict__ wgru,
      const bf16* __restrict__ conv_bias, const bf16* __restrict__ bih,
      const bf16* __restrict__ bhh, int N_){
  __shared__ unsigned short Sb[80*SB];
  __shared__ int kp[81];
  __shared__ unsigned char pm[80];
  __shared__ char ubuf[SRCCAP*4];            // srcL (phase 0/1) | m_s (phase 2/3)
  int* srcL = (int*)ubuf;
  unsigned short* m_s = (unsigned short*)ubuf;
  int tid=threadIdx.x, lane=tid&63, w=tid>>6;
  int b=blockIdx.x;
  if (tid<81) kp[tid]=kptr[(size_t)b*80+tid];
  if (tid<80) pm[tid]=kperm[(size_t)b*80+tid];
  __syncthreads();
  int s0g = kp[0];
  int elen = kp[80]-s0g;
  int cap = (elen<=SRCCAP)? elen : 0;        // fallback: read global if oversized
  for (int i=tid;i<cap;i+=256) srcL[i]=sorted_src[s0g+i]<<6;  // premultiplied (elements)
  __syncthreads();
  int g=lane>>3, c=lane&7;
  const bf16* hp = hin + c*8;

  // ---- phase 1 ----
  auto run_phase1 = [&](auto GET){
    #pragma unroll 1
    for (int jo=0;jo<5;jo++){
      int pbase = jo*16 + w*4;
      int p  = pm[pbase + (g&3)];
      int p0 = pm[pbase];
      int st = kp[p]-s0g, len = kp[p+1]-kp[p];
      int maxLen = kp[p0+1]-kp[p0];          // rank-0 key is longest of the 4
      int sub = g>>2;
      float a[8];
      #pragma unroll
      for (int j=0;j<8;j++) a[j]=0.f;
      for (int base=0; base<maxLen; base+=8){
        uint4 hv[4];
        #pragma unroll
        for (int u=0;u<4;u++){
          int idx = base + sub*4 + u;
          hv[u].x=0u; hv[u].y=0u; hv[u].z=0u; hv[u].w=0u;
          if (idx < len){
            int s = GET(st+idx);
            hv[u] = *(const uint4*)(hp + (size_t)s);
          }
        }
        #pragma unroll
        for (int u=0;u<4;u++){
          a[0]+=lo16f(hv[u].x); a[1]+=hi16f(hv[u].x);
          a[2]+=lo16f(hv[u].y); a[3]+=hi16f(hv[u].y);
          a[4]+=lo16f(hv[u].z); a[5]+=hi16f(hv[u].z);
          a[6]+=lo16f(hv[u].w); a[7]+=hi16f(hv[u].w);
        }
      }
      #pragma unroll
      for (int j=0;j<8;j++) a[j] += __shfl_xor(a[j], 32);
      if (g<4){
        short8 v;
        #pragma unroll
        for (int j=0;j<8;j++) v[j] = f2bits(a[j]);
        *reinterpret_cast<short8*>(&Sb[(size_t)p*SB + c*8]) = v;
      }
    }
  };
  if (cap) run_phase1([&](int rel){ return srcL[rel]; });
  else     run_phase1([&](int rel){ return sorted_src[s0g+rel]<<6; });
  __syncthreads();

  // ---- phase 2: wave w -> coltile ct=w ----
  int q=lane>>4, mr=lane&15;
  {
    int ct = w;
    f32x4 acc={0.f,0.f,0.f,0.f};
    #pragma unroll
    for (int ks=0;ks<10;ks++){
      int k0 = ks*32 + q*8;
      int tt = k0>>6, ch = k0&63;
      short8 af = *reinterpret_cast<const short8*>(&Sb[(size_t)(mr*5+tt)*SB + ch]);
      short8 bfrag = *(const short8*)(wall + (size_t)((ct*10+ks)*64+lane)*8);
      acc = MFMA16(af, bfrag, acc);
    }
    int col = ct*16+mr;
    float bi = b2f(conv_bias[col]);
    #pragma unroll
    for (int r=0;r<4;r++){
      int nl = q*4+r;
      int deg = kp[nl*5+5]-kp[nl*5];
      float dv = 1.f/fmaxf((float)deg,1.f);
      m_s[nl*MSTR+col] = (unsigned short)f2bits(fmaxf(acc[r]*dv+bi,0.f));
    }
  }
  __syncthreads();

  // ---- phase 3: GRU, wave w -> coltile cc=w ----
  {
    int cc = w;
    int na = b*16+mr; if (na>N_-1) na=N_-1;
    short8 am0 = *(const short8*)(&m_s[mr*MSTR + q*8]);
    short8 am1 = *(const short8*)(&m_s[mr*MSTR + 32 + q*8]);
    short8 ah0 = ld_frag(hin + (size_t)na*64 + q*8);
    short8 ah1 = ld_frag(hin + (size_t)na*64 + 32 + q*8);
    const short8* Bw = reinterpret_cast<const short8*>(wgru);
    f32x4 xr={0.f,0.f,0.f,0.f}, xz=xr, xn=xr, hr=xr, hz=xr, hn=xr;
    xr = MFMA16(am0, Bw[((cc  )*2+0)*64+lane], xr);
    xr = MFMA16(am1, Bw[((cc  )*2+1)*64+lane], xr);
    xz = MFMA16(am0, Bw[((cc+4)*2+0)*64+lane], xz);
    xz = MFMA16(am1, Bw[((cc+4)*2+1)*64+lane], xz);
    xn = MFMA16(am0, Bw[((cc+8)*2+0)*64+lane], xn);
    xn = MFMA16(am1, Bw[((cc+8)*2+1)*64+lane], xn);
    hr = MFMA16(ah0, Bw[(24+(cc  )*2+0)*64+lane], hr);
    hr = MFMA16(ah1, Bw[(24+(cc  )*2+1)*64+lane], hr);
    hz = MFMA16(ah0, Bw[(24+(cc+4)*2+0)*64+lane], hz);
    hz = MFMA16(ah1, Bw[(24+(cc+4)*2+1)*64+lane], hz);
    hn = MFMA16(ah0, Bw[(24+(cc+8)*2+0)*64+lane], hn);
    hn = MFMA16(ah1, Bw[(24+(cc+8)*2+1)*64+lane], hn);
    int col = cc*16+mr;
    float bxr=b2f(bih[col]), bxz=b2f(bih[col+64]), bxn=b2f(bih[col+128]);
    float bhr=b2f(bhh[col]), bhz=b2f(bhh[col+64]), bhn=b2f(bhh[col+128]);
    #pragma unroll
    for (int r=0;r<4;r++){
      int row = q*4+r;
      int n = b*16+row;
      if (n < N_){
        float rg = sigmf(xr[r]+bxr + hr[r]+bhr);
        float zg = sigmf(xz[r]+bxz + hz[r]+bhz);
        float ng = tanhfast(xn[r]+bxn + rg*(hn[r]+bhn));
        float ho = b2f(hin[(size_t)n*64+col]);
        hout[(size_t)n*64+col] = f2b((1.f-zg)*ng + zg*ho);
      }
    }
  }
}

// ---------------- fused readout: (read1 + read2) ----------------
// 64 nodes / block. Stage 1 computes s1,t1 into LDS (C-layout write),
// stage 2 re-reads them as A-frags and does the K=64 GEMMs to `gated`.
__global__ __launch_bounds__(256) void k_read(const bf16* __restrict__ h, const bf16* __restrict__ out0,
      const unsigned short* __restrict__ W, const bf16* __restrict__ ib1, const bf16* __restrict__ jb1,
      const unsigned short* __restrict__ iw2swz, const unsigned short* __restrict__ jw2swz,
      const bf16* __restrict__ ib2, const bf16* __restrict__ jb2,
      float* __restrict__ gated, int N_){
  __shared__ unsigned short lds[12288];      // iw1swz(8192) | jw1swz(4096)
  __shared__ unsigned short sbuf[64*72];
  __shared__ unsigned short tbuf[64*72];
  { const int* s=(const int*)W; int* d=(int*)lds;
    for (int i=threadIdx.x;i<6144;i+=256) d[i]=s[i]; }
  __syncthreads();
  int tid=threadIdx.x, lane=tid&63, w=tid>>6, q=lane>>4;
  int nb = blockIdx.x*64 + w*16;
  int ar = nb + (lane&15); if (ar>N_-1) ar=N_-1;
  short8 ah0 = ld_frag(h + (size_t)ar*64 + q*8),    ah1 = ld_frag(h + (size_t)ar*64 + 32 + q*8);
  short8 ao0 = ld_frag(out0 + (size_t)ar*64 + q*8), ao1 = ld_frag(out0 + (size_t)ar*64 + 32 + q*8);
  const short8* Bi = reinterpret_cast<const short8*>(lds);
  const short8* Bj = reinterpret_cast<const short8*>(lds + 8192);
  int colb = lane&15;
  for (int cb=0; cb<4; cb++){
    f32x4 ai = {0.f,0.f,0.f,0.f};
    ai = MFMA16(ah0, Bi[(cb*4+0)*64+lane], ai);
    ai = MFMA16(ah1, Bi[(cb*4+1)*64+lane], ai);
    ai = MFMA16(ao0, Bi[(cb*4+2)*64+lane], ai);
    ai = MFMA16(ao1, Bi[(cb*4+3)*64+lane], ai);
    f32x4 aj = {0.f,0.f,0.f,0.f};
    aj = MFMA16(ah0, Bj[(cb*2+0)*64+lane], aj);
    aj = MFMA16(ah1, Bj[(cb*2+1)*64+lane], aj);
    int col = cb*16 + colb;
    float bi=b2f(ib1[col]), bj=b2f(jb1[col]);
    #pragma unroll
    for (int r=0;r<4;r++){
      int lrow = w*16 + q*4 + r;
      sbuf[lrow*72+col] = (unsigned short)f2bits(sigmf(ai[r]+bi));
      tbuf[lrow*72+col] = (unsigned short)f2bits(sigmf(aj[r]+bj));
    }
  }
  __syncthreads();
  // stage 2: K=64 GEMMs from LDS A-frags
  int mr = lane&15;
  short8 as0 = *(const short8*)(&sbuf[(w*16+mr)*72 + q*8]);
  short8 as1 = *(const short8*)(&sbuf[(w*16+mr)*72 + 32 + q*8]);
  short8 at0 = *(const short8*)(&tbuf[(w*16+mr)*72 + q*8]);
  short8 at1 = *(const short8*)(&tbuf[(w*16+mr)*72 + 32 + q*8]);
  const short8* Bi2 = reinterpret_cast<const short8*>(iw2swz);
  const short8* Bj2 = reinterpret_cast<const short8*>(jw2swz);
  f32x4 ai = {0.f,0.f,0.f,0.f};
  ai = MFMA16(as0, Bi2[lane], ai);
  ai = MFMA16(as1, Bi2[64+lane], ai);
  f32x4 aj = {0.f,0.f,0.f,0.f};
  aj = MFMA16(at0, Bj2[lane], aj);
  aj = MFMA16(at1, Bj2[64+lane], aj);
  int col = lane&15;
  if (col<12){
    float bi=b2f(ib2[col]), bj=b2f(jb2[col]);
    #pragma unroll
    for (int r=0;r<4;r++){
      int row = nb + q*4 + r;
      if (row < N_) gated[(size_t)row*12+col] = sigmf(ai[r]+bi)*(aj[r]+bj);
    }
  }
}

__global__ __launch_bounds__(256) void k_graphsum(const float* __restrict__ gated,
      const int* __restrict__ gptr, const int* __restrict__ flag, void* __restrict__ outp){
  int g = blockIdx.x;
  int s = gptr[g], e = gptr[g+1];
  int tid = threadIdx.x;
  int c = tid & 15, rg = tid >> 4;
  float acc = 0.f;
  if (c < 12)
    for (int row = s + rg; row < e; row += 16) acc += gated[(size_t)row*12 + c];
  __shared__ float sm[256];
  sm[tid] = acc;
  __syncthreads();
  if (rg == 0 && c < 12){
    float t = 0.f;
    for (int k=0;k<16;k++) t += sm[k*16 + c];
    if (*flag) ((float*)outp)[g*12 + c] = t;
    else       ((bf16*) outp)[g*12 + c] = f2b(t);
  }
}

// ---------------- launch ----------------

extern "C" void kernel_launch(void* const* d_in, const int* in_sizes, int n_in,
                              void* d_out, int out_size, void* d_ws, size_t ws_size,
                              hipStream_t stream){
  const int*  ei    = (const int*) d_in[1];
  const int*  ea    = (const int*) d_in[2];
  const int*  batch = (const int*) d_in[3];

  const int N_ = in_sizes[3];        // 100000
  const int E_ = in_sizes[2];        // 3200000
  const int G_ = out_size / 12;      // 256
  const int nb  = (N_ + 31) >> 5;    // 3125 bins of 32 nodes (sort pipeline)
  const int nbs = (N_ + 15) >> 4;    // 6250 buckets of 16 nodes (step kernel)

  char* ws = (char*)d_ws;
  size_t off = 0;
  auto alloc = [&](size_t bytes)->size_t{
    size_t o = off; off += (bytes + 255) & ~(size_t)255; return o;
  };

  size_t oOut0   = alloc((size_t)N_*64*2);
  size_t oH0     = alloc((size_t)N_*64*2);
  size_t oH1     = alloc((size_t)N_*64*2);
  size_t oGated  = alloc((size_t)N_*12*4);
  size_t oBEdges = alloc((size_t)E_*4);
  size_t oSorted = alloc((size_t)E_*4);
  size_t oKptr   = alloc(((size_t)nb*160+2)*4);
  size_t oKperm  = alloc((size_t)nb*160);
  size_t oCanon  = alloc((size_t)CAN_TOT*2);
  size_t oCnt    = alloc((size_t)nb*4);
  size_t oBPtr   = alloc((size_t)(nb+1)*4);
  size_t oBCur   = alloc((size_t)nb*4);
  size_t oGptr   = alloc((size_t)(G_+1)*4);
  size_t oFlag   = alloc(256);
  size_t oWall   = alloc((size_t)20480*2);
  size_t oWgru   = alloc((size_t)24576*2);
  size_t oWr1    = alloc((size_t)12288*2);
  size_t oWiw2   = alloc((size_t)1024*2);
  size_t oWjw2   = alloc((size_t)1024*2);

  bf16*  out0    = (bf16*)(ws + oOut0);
  bf16*  h0      = (bf16*)(ws + oH0);
  bf16*  h1      = (bf16*)(ws + oH1);
  float* gated   = (float*)(ws + oGated);
  unsigned int* bucketed = (unsigned int*)(ws + oBEdges);
  int*   sorted_src = (int*)(ws + oSorted);
  int*   kptr    = (int*)(ws + oKptr);
  unsigned char* kperm = (unsigned char*)(ws + oKperm);
  bf16*  can     = (bf16*)(ws + oCanon);
  int*   bkt_cnt = (int*)(ws + oCnt);
  int*   bkt_ptr = (int*)(ws + oBPtr);
  int*   bkt_cur = (int*)(ws + oBCur);
  int*   gptr    = (int*)(ws + oGptr);
  int*   flag    = (int*)(ws + oFlag);
  unsigned short* wall  = (unsigned short*)(ws + oWall);
  unsigned short* wgru  = (unsigned short*)(ws + oWgru);
  unsigned short* wr1   = (unsigned short*)(ws + oWr1);
  unsigned short* wiw2s = (unsigned short*)(ws + oWiw2);
  unsigned short* wjw2s = (unsigned short*)(ws + oWjw2);

  const bf16* xC    = can + CAN_X;
  const bf16* l0wC  = can + CAN_L0W;
  const bf16* l0bC  = can + CAN_L0B;
  const bf16* eeC   = can + CAN_EE;
  const bf16* cbC   = can + CAN_CB;
  const bf16* wihC  = can + CAN_WIH;
  const bf16* whhC  = can + CAN_WHH;
  const bf16* bihC  = can + CAN_BIH;
  const bf16* bhhC  = can + CAN_BHH;
  const bf16* iw1C  = can + CAN_IW1;
  const bf16* ib1C  = can + CAN_IB1;
  const bf16* iw2C  = can + CAN_IW2;
  const bf16* ib2C  = can + CAN_IB2;
  const bf16* jw1C  = can + CAN_JW1;
  const bf16* jb1C  = can + CAN_JB1;
  const bf16* jw2C  = can + CAN_JW2;
  const bf16* jb2C  = can + CAN_JB2;

  PtrPack pk;
  pk.p[0]=d_in[0];  pk.p[1]=d_in[4];  pk.p[2]=d_in[5];  pk.p[3]=d_in[6];
  pk.p[4]=d_in[7];  pk.p[5]=d_in[8];  pk.p[6]=d_in[9];  pk.p[7]=d_in[10];
  pk.p[8]=d_in[11]; pk.p[9]=d_in[12]; pk.p[10]=d_in[13]; pk.p[11]=d_in[14];
  pk.p[12]=d_in[15]; pk.p[13]=d_in[16]; pk.p[14]=d_in[17]; pk.p[15]=d_in[18];
  pk.p[16]=d_in[19];

  const int gNw  = (N_+63)/64;       // 64 nodes / block (readout)
  const int gEc  = (E_+4095)/4096;   // 4096-edge chunks

  // --- setup ---
  k_sniff<<<1, 256, 0, stream>>>((const unsigned int*)d_in[0], flag);
  k_canon<<<(CAN_TOT+255)/256, 256, 0, stream>>>(pk, flag, can);
  hipMemsetAsync(ws + oCnt, 0, (size_t)nb*4, stream);
  k_bcount<<<gEc, 256, 0, stream>>>(ei + E_, E_, nb, bkt_cnt);
  k_scan<<<1, 1024, 0, stream>>>(bkt_cnt, nb, bkt_ptr, bkt_cur);
  k_bscatter<<<gEc, 256, 0, stream>>>(ei, ei + E_, ea, E_, nb, bkt_cur, bucketed);
  k_bsort<<<nb, 256, 0, stream>>>(bucketed, bkt_ptr, nb, E_, kptr, sorted_src, kperm);
  k_lin0<<<(N_*64+255)/256, 256, 0, stream>>>(xC, l0wC, l0bC, out0, h0, N_);
  k_prep<<<32, 256, 0, stream>>>(eeC, wihC, whhC, iw1C, jw1C, iw2C, jw2C,
                                 wall, wgru, wr1, wiw2s, wjw2s, batch, N_, G_, gptr);

  // --- 6 propagation steps (double-buffered h) ---
  bf16* hb[2] = {h0, h1};
  for (int step = 0; step < 6; ++step){
    k_step<<<nbs, 256, 0, stream>>>(hb[step&1], hb[(step+1)&1], sorted_src, kptr, kperm,
                                    wall, wgru, cbC, bihC, bhhC, N_);
  }
  bf16* hfin = hb[0];   // after 6 steps

  // --- readout ---
  k_read<<<gNw, 256, 0, stream>>>(hfin, out0, wr1, ib1C, jb1C, wiw2s, wjw2s,
                                  ib2C, jb2C, gated, N_);
  k_graphsum<<<G_, 256, 0, stream>>>(gated, gptr, flag, d_out);
}